// Round 1
// 1201.359 us; speedup vs baseline: 1.3499x; 1.3499x over previous
//
#include <hip/hip_runtime.h>
#include <hip/hip_bf16.h>

// AdaptiveEdgeGAT: N=50000, E=800000, IN=OUT=128, EDGE=64, H=4, D=32
// CSR (sort-by-dst) + gather-based segmented reductions: zero data-path atomics.
// Dual-mode input read (bf16 or f32, device-detected), f32 accumulation.
// R1: k_node_agg rewritten wave-per-node (4 nodes/block, 1 barrier, reg softmax,
//     4x-unrolled gather, W_edge^T column in VGPRs) to attack latency-bound profile.

#define N_NODES 50000
#define N_EDGES 800000
#define IN_DIM 128
#define OUT_DIM 128
#define EDGE_DIM 64
#define HEADS 4
#define HEAD_DIM 32
#define NEG_SLOPE 0.2f

typedef __hip_bfloat16 bf16;
typedef unsigned short u16;
typedef unsigned int u32;
typedef unsigned long long u64;

// canonical f32 weight-block offsets (floats)
#define OFF_WSRC 0
#define OFF_BSRC 16384
#define OFF_WDST 16512
#define OFF_BDST 32896
#define OFF_ATTN 33024
#define OFF_WEDGE 33152
#define OFF_BEDGE 41344
#define OFF_WGATE 41472
#define OFF_BGATE 74240
#define OFF_WOUT 74368
#define OFF_BOUT 90752
#define OFF_WEDGE_T 90880   // transposed W_edge: [col][k] = [128][64]
#define W_TOTAL 99072

__device__ __forceinline__ float b2f_raw(u16 v) {
    return __uint_as_float(((u32)v) << 16);
}
__device__ __forceinline__ float b2f(bf16 v) { return __bfloat162float(v); }
__device__ __forceinline__ float loadin(const void* p, long i, int isbf) {
    return isbf ? b2f_raw(((const u16*)p)[i]) : ((const float*)p)[i];
}
__device__ __forceinline__ float lo16(u32 v) { return __uint_as_float(v << 16); }
__device__ __forceinline__ float hi16(u32 v) { return __uint_as_float(v & 0xFFFF0000u); }
__device__ __forceinline__ u16 f2b_bits(float x) {
    bf16 t = __float2bfloat16(x);
    return *reinterpret_cast<u16*>(&t);
}

// ---------- dtype detector ----------
__global__ __launch_bounds__(256) void k_detect(const void* node, int* flag) {
    __shared__ int cnt[256];
    int c = 0;
    for (int i = threadIdx.x; i < 8192; i += 256) {
        float v = b2f_raw(((const u16*)node)[i]);
        float a = fabsf(v);
        if ((a >= 1e-4f && a <= 50.f) || v == 0.f) c++;
    }
    cnt[threadIdx.x] = c;
    __syncthreads();
    for (int s = 128; s > 0; s >>= 1) {
        if (threadIdx.x < s) cnt[threadIdx.x] += cnt[threadIdx.x + s];
        __syncthreads();
    }
    if (threadIdx.x == 0) flag[0] = (cnt[0] >= (8192 * 85) / 100) ? 1 : 0;
}

// ---------- canonicalize weights to f32 (+ transposed W_edge) ----------
__global__ __launch_bounds__(256) void k_wconv(const void* Wsrc, const void* bsrc,
                                               const void* Wdst, const void* bdst,
                                               const void* attn, const void* Wedge, const void* bedge,
                                               const void* Wgate, const void* bgate,
                                               const void* Wout, const void* bout,
                                               float* w, const int* flag) {
    int i = blockIdx.x * 256 + threadIdx.x;
    if (i >= W_TOTAL) return;
    int f = flag[0];
    const void* p; long off;
    if (i < OFF_BSRC)         { p = Wsrc;  off = i - OFF_WSRC; }
    else if (i < OFF_WDST)    { p = bsrc;  off = i - OFF_BSRC; }
    else if (i < OFF_BDST)    { p = Wdst;  off = i - OFF_WDST; }
    else if (i < OFF_ATTN)    { p = bdst;  off = i - OFF_BDST; }
    else if (i < OFF_WEDGE)   { p = attn;  off = i - OFF_ATTN; }
    else if (i < OFF_BEDGE)   { p = Wedge; off = i - OFF_WEDGE; }
    else if (i < OFF_WGATE)   { p = bedge; off = i - OFF_BEDGE; }
    else if (i < OFF_BGATE)   { p = Wgate; off = i - OFF_WGATE; }
    else if (i < OFF_WOUT)    { p = bgate; off = i - OFF_BGATE; }
    else if (i < OFF_BOUT)    { p = Wout;  off = i - OFF_WOUT; }
    else if (i < OFF_WEDGE_T) { p = bout;  off = i - OFF_BOUT; }
    else { // transposed W_edge: wt[col*64+k] = W_edge[k*128+col]
        int idx = i - OFF_WEDGE_T;
        int col = idx >> 6, k = idx & 63;
        w[i] = loadin(Wedge, (long)k * OUT_DIM + col, f);
        return;
    }
    w[i] = loadin(p, off, f);
}

// ---------- zero degree counters ----------
__global__ __launch_bounds__(256) void k_zero(int* __restrict__ deg) {
    int i = blockIdx.x * 256 + threadIdx.x;
    if (i < N_NODES) deg[i] = 0;
}

// ---------- degree histogram ----------
__global__ __launch_bounds__(256) void k_hist(const int* __restrict__ dst, int* __restrict__ deg) {
    int e = blockIdx.x * 256 + threadIdx.x;
    if (e < N_EDGES) atomicAdd(&deg[dst[e]], 1);
}

// ---------- exclusive prefix sum (single block) -> rowptr, cursor ----------
__global__ __launch_bounds__(1024) void k_scan(const int* __restrict__ deg,
                                               int* __restrict__ rowptr,
                                               int* __restrict__ cursor) {
    __shared__ int buf[1024];
    __shared__ int carry;
    int tid = threadIdx.x;
    if (tid == 0) carry = 0;
    __syncthreads();
    for (int base = 0; base <= N_NODES; base += 1024) {
        int i = base + tid;
        int v = (i < N_NODES) ? deg[i] : 0;
        buf[tid] = v;
        __syncthreads();
        for (int s = 1; s < 1024; s <<= 1) {
            int add = (tid >= s) ? buf[tid - s] : 0;
            __syncthreads();
            buf[tid] += add;
            __syncthreads();
        }
        int excl = carry + buf[tid] - v;
        if (i <= N_NODES) {
            rowptr[i] = excl;
            if (i < N_NODES) cursor[i] = excl;
        }
        __syncthreads();
        if (tid == 1023) carry += buf[1023];
        __syncthreads();
    }
}

// ---------- scatter edge ids into dst-sorted order ----------
__global__ __launch_bounds__(256) void k_permute(const int* __restrict__ dst,
                                                 int* __restrict__ cursor, int* __restrict__ perm) {
    int e = blockIdx.x * 256 + threadIdx.x;
    if (e >= N_EDGES) return;
    int p = atomicAdd(&cursor[dst[e]], 1);
    perm[p] = e;
}

// ---------- node projections ----------
#define PROJ_ROWS 16
__global__ __launch_bounds__(128) void k_proj(const void* __restrict__ node,
                                              const float* __restrict__ w, const int* __restrict__ flag,
                                              bf16* __restrict__ f_src, bf16* __restrict__ f_dst) {
    __shared__ float lds[PROJ_ROWS][IN_DIM];
    int isbf = flag[0];
    int col = threadIdx.x;
    long row0 = (long)blockIdx.x * PROJ_ROWS;
    for (int i = col; i < PROJ_ROWS * IN_DIM; i += 128)
        lds[i >> 7][i & 127] = loadin(node, row0 * IN_DIM + i, isbf);
    __syncthreads();
    float accs[PROJ_ROWS], accd[PROJ_ROWS];
    float bsv = w[OFF_BSRC + col], bdv = w[OFF_BDST + col];
#pragma unroll
    for (int r = 0; r < PROJ_ROWS; r++) { accs[r] = bsv; accd[r] = bdv; }
    for (int k = 0; k < IN_DIM; k++) {
        float ws = w[OFF_WSRC + k * OUT_DIM + col];
        float wd = w[OFF_WDST + k * OUT_DIM + col];
#pragma unroll
        for (int r = 0; r < PROJ_ROWS; r++) {
            float x = lds[r][k];
            accs[r] += x * ws;
            accd[r] += x * wd;
        }
    }
#pragma unroll
    for (int r = 0; r < PROJ_ROWS; r++) {
        f_src[(row0 + r) * OUT_DIM + col] = __float2bfloat16(accs[r]);
        f_dst[(row0 + r) * OUT_DIM + col] = __float2bfloat16(accd[r]);
    }
}

// ---------- per-edge GATv2 logits (no atomics) ----------
__global__ __launch_bounds__(256) void k_logits(const bf16* __restrict__ f_src,
                                                const bf16* __restrict__ f_dst,
                                                const int* __restrict__ src, const int* __restrict__ dst,
                                                const float* __restrict__ w,
                                                bf16* __restrict__ logits) {
    __shared__ float aw[HEADS * HEAD_DIM];
    if (threadIdx.x < HEADS * HEAD_DIM) aw[threadIdx.x] = w[OFF_ATTN + threadIdx.x];
    __syncthreads();
    int t = blockIdx.x * 256 + threadIdx.x;
    int e = t >> 2, h = t & 3;
    if (e >= N_EDGES) return;
    int s = src[e], d = dst[e];
    const bf16* ps = f_src + (long)s * OUT_DIM + h * HEAD_DIM;
    const bf16* pd = f_dst + (long)d * OUT_DIM + h * HEAD_DIM;
    float acc = 0.f;
#pragma unroll
    for (int i = 0; i < HEAD_DIM; i++) {
        float v = b2f(ps[i]) + b2f(pd[i]);
        v = v > 0.f ? v : NEG_SLOPE * v;
        acc += v * aw[h * HEAD_DIM + i];
    }
    logits[(long)e * HEADS + h] = __float2bfloat16(acc);
}

// ---------- per-node aggregation: wave-per-node, 4 nodes per 256-thr block ----------
// Phase 1: lane j owns edge j (deg<=64 hot path); stage edge_feat rows (cap 32) to LDS.
// Phase 2: register softmax via shfl_xor tree; a -> LDS f32 + packed out_a store.
// Phase 3 (after the single barrier): 4x-unrolled f_src gather (u32 = 2 cols/lane),
//          then edge-encoder GEMM with W_edge^T column resident in 64 VGPRs,
//          x broadcast-read from LDS. No other barriers; waves fully independent.
#define CAPX 32   // staged edge rows per node (overflow -> global broadcast reads)
__global__ __launch_bounds__(256, 4) void k_node_agg(const int* __restrict__ rowptr,
                                                  const int* __restrict__ perm,
                                                  const int* __restrict__ src,
                                                  const bf16* __restrict__ f_src,
                                                  const bf16* __restrict__ logits,
                                                  const void* __restrict__ edge_feat,
                                                  const float* __restrict__ w, const int* __restrict__ flag,
                                                  bf16* __restrict__ h_node, bf16* __restrict__ edge_max,
                                                  bf16* __restrict__ out_a_b, float* __restrict__ out_a_f) {
    __shared__ int s_esrc[4][64];
    __shared__ __align__(16) float s_a[4][64][4];
    __shared__ __align__(16) float s_xs[4][CAPX][EDGE_DIM];

    const int wv = threadIdx.x >> 6;
    const int lane = threadIdx.x & 63;
    const int n = blockIdx.x * 4 + wv;
    const int isbf = flag[0];
    const int r0 = rowptr[n], r1 = rowptr[n + 1];
    const int deg = r1 - r0;

    int* esrc = s_esrc[wv];
    float (*aA)[4] = s_a[wv];
    float (*xs)[EDGE_DIM] = s_xs[wv];

    // ---- Phase 1: per-lane edge metadata + edge_feat staging ----
    int e0 = 0;
    float l0 = -3.0e38f, l1 = -3.0e38f, l2 = -3.0e38f, l3 = -3.0e38f;
    if (lane < deg) {
        e0 = perm[r0 + lane];
        esrc[lane] = src[e0];
        u64 lw = ((const u64*)logits)[e0];
        l0 = b2f_raw((u16)lw);
        l1 = b2f_raw((u16)(lw >> 16));
        l2 = b2f_raw((u16)(lw >> 32));
        l3 = b2f_raw((u16)(lw >> 48));
    }
    const int jm = deg < CAPX ? deg : CAPX;
    for (int j = 0; j < jm; j++) {
        int e = __shfl(e0, j);   // broadcast edge id from lane j
        xs[j][lane] = loadin(edge_feat, (long)e * EDGE_DIM + lane, isbf);
    }

    // ---- Phase 2: softmax stats in registers ----
    float m0 = l0, m1 = l1, m2 = l2, m3 = l3;
    for (int j = lane + 64; j < deg; j += 64) {   // cold: deg > 64 (never for Poisson(16))
        u64 lw = ((const u64*)logits)[perm[r0 + j]];
        m0 = fmaxf(m0, b2f_raw((u16)lw));
        m1 = fmaxf(m1, b2f_raw((u16)(lw >> 16)));
        m2 = fmaxf(m2, b2f_raw((u16)(lw >> 32)));
        m3 = fmaxf(m3, b2f_raw((u16)(lw >> 48)));
    }
#pragma unroll
    for (int s = 1; s < 64; s <<= 1) {
        m0 = fmaxf(m0, __shfl_xor(m0, s));
        m1 = fmaxf(m1, __shfl_xor(m1, s));
        m2 = fmaxf(m2, __shfl_xor(m2, s));
        m3 = fmaxf(m3, __shfl_xor(m3, s));
    }
    float p0 = 0.f, p1 = 0.f, p2 = 0.f, p3 = 0.f;
    if (lane < deg) {
        p0 = __expf(l0 - m0); p1 = __expf(l1 - m1);
        p2 = __expf(l2 - m2); p3 = __expf(l3 - m3);
    }
    float t0 = p0, t1 = p1, t2 = p2, t3 = p3;
    for (int j = lane + 64; j < deg; j += 64) {   // cold
        u64 lw = ((const u64*)logits)[perm[r0 + j]];
        t0 += __expf(b2f_raw((u16)lw) - m0);
        t1 += __expf(b2f_raw((u16)(lw >> 16)) - m1);
        t2 += __expf(b2f_raw((u16)(lw >> 32)) - m2);
        t3 += __expf(b2f_raw((u16)(lw >> 48)) - m3);
    }
#pragma unroll
    for (int s = 1; s < 64; s <<= 1) {
        t0 += __shfl_xor(t0, s);
        t1 += __shfl_xor(t1, s);
        t2 += __shfl_xor(t2, s);
        t3 += __shfl_xor(t3, s);
    }
    const float i0 = 1.f / fmaxf(t0, 1e-9f);
    const float i1 = 1.f / fmaxf(t1, 1e-9f);
    const float i2 = 1.f / fmaxf(t2, 1e-9f);
    const float i3 = 1.f / fmaxf(t3, 1e-9f);
    if (lane < deg) {
        float a0 = p0 * i0, a1 = p1 * i1, a2 = p2 * i2, a3 = p3 * i3;
        *(float4*)aA[lane] = make_float4(a0, a1, a2, a3);
        if (isbf) {
            u64 pk = (u64)f2b_bits(a0) | ((u64)f2b_bits(a1) << 16)
                   | ((u64)f2b_bits(a2) << 32) | ((u64)f2b_bits(a3) << 48);
            ((u64*)out_a_b)[e0] = pk;
        } else {
            ((float4*)out_a_f)[e0] = make_float4(a0, a1, a2, a3);
        }
    }
    for (int j = lane + 64; j < deg; j += 64) {   // cold: out_a for overflow edges
        int e = perm[r0 + j];
        u64 lw = ((const u64*)logits)[e];
        float a0 = __expf(b2f_raw((u16)lw) - m0) * i0;
        float a1 = __expf(b2f_raw((u16)(lw >> 16)) - m1) * i1;
        float a2 = __expf(b2f_raw((u16)(lw >> 32)) - m2) * i2;
        float a3 = __expf(b2f_raw((u16)(lw >> 48)) - m3) * i3;
        if (isbf) {
            u64 pk = (u64)f2b_bits(a0) | ((u64)f2b_bits(a1) << 16)
                   | ((u64)f2b_bits(a2) << 32) | ((u64)f2b_bits(a3) << 48);
            ((u64*)out_a_b)[e] = pk;
        } else {
            ((float4*)out_a_f)[e] = make_float4(a0, a1, a2, a3);
        }
    }

    __syncthreads();   // the only barrier: LDS (esrc, aA, xs) now visible wave-wide

    // ---- Phase 3a: message gather. lane owns bf16 column pair (2*lane, 2*lane+1) ----
    const int hsel = lane >> 4;               // head of this column pair
    const u32* fs32 = (const u32*)f_src;
    float acc0 = 0.f, acc1 = 0.f;
    const int dm = deg < 64 ? deg : 64;
    int j = 0;
    for (; j + 4 <= dm; j += 4) {
        int s0 = esrc[j], s1 = esrc[j + 1], s2 = esrc[j + 2], s3 = esrc[j + 3];
        float a0 = aA[j][hsel], a1 = aA[j + 1][hsel];
        float a2 = aA[j + 2][hsel], a3 = aA[j + 3][hsel];
        u32 v0 = fs32[s0 * 64 + lane];
        u32 v1 = fs32[s1 * 64 + lane];
        u32 v2 = fs32[s2 * 64 + lane];
        u32 v3 = fs32[s3 * 64 + lane];
        acc0 += lo16(v0) * a0 + lo16(v1) * a1 + lo16(v2) * a2 + lo16(v3) * a3;
        acc1 += hi16(v0) * a0 + hi16(v1) * a1 + hi16(v2) * a2 + hi16(v3) * a3;
    }
    for (; j < dm; j++) {
        int s0 = esrc[j];
        float a0 = aA[j][hsel];
        u32 v0 = fs32[s0 * 64 + lane];
        acc0 += lo16(v0) * a0;
        acc1 += hi16(v0) * a0;
    }
    if (deg > 64) {   // cold
        float mh = (hsel & 2) ? ((hsel & 1) ? m3 : m2) : ((hsel & 1) ? m1 : m0);
        float ih = (hsel & 2) ? ((hsel & 1) ? i3 : i2) : ((hsel & 1) ? i1 : i0);
        for (int jj = 64; jj < deg; jj++) {
            int e = perm[r0 + jj];
            int s0 = src[e];
            float lg = b2f_raw(((const u16*)logits)[(long)e * 4 + hsel]);
            float aj = __expf(lg - mh) * ih;
            u32 v0 = fs32[s0 * 64 + lane];
            acc0 += lo16(v0) * aj;
            acc1 += hi16(v0) * aj;
        }
    }
    ((u32*)h_node)[n * 64 + lane] =
        (u32)f2b_bits(acc0) | ((u32)f2b_bits(acc1) << 16);

    // ---- Phase 3b: edge encoder GEMM + running max (2 column passes) ----
#pragma unroll 1
    for (int p = 0; p < 2; p++) {
        const int col = lane + p * 64;
        const float4* wt4 = (const float4*)(w + OFF_WEDGE_T + col * EDGE_DIM);
        float4 wvv[16];
#pragma unroll
        for (int kk = 0; kk < 16; kk++) wvv[kk] = wt4[kk];
        const float bias = w[OFF_BEDGE + col];
        float vmax = -3.0e38f;
        const int jm2 = deg < CAPX ? deg : CAPX;
        for (int jj = 0; jj < jm2; jj++) {
            const float4* x4 = (const float4*)xs[jj];
            float acc = bias;
#pragma unroll
            for (int kk = 0; kk < 16; kk++) {
                float4 x = x4[kk];
                acc += x.x * wvv[kk].x + x.y * wvv[kk].y + x.z * wvv[kk].z + x.w * wvv[kk].w;
            }
            vmax = fmaxf(vmax, acc > 0.f ? acc : __expf(acc) - 1.f);
        }
        for (int jj = CAPX; jj < deg; jj++) {   // overflow rows: global broadcast reads
            long e = perm[r0 + jj];
            float acc = bias;
            if (isbf) {
                const u64* rp = (const u64*)edge_feat + e * 16;
#pragma unroll
                for (int kk = 0; kk < 16; kk++) {
                    u64 q = rp[kk];
                    acc += b2f_raw((u16)q) * wvv[kk].x
                         + b2f_raw((u16)(q >> 16)) * wvv[kk].y
                         + b2f_raw((u16)(q >> 32)) * wvv[kk].z
                         + b2f_raw((u16)(q >> 48)) * wvv[kk].w;
                }
            } else {
                const float4* rp = (const float4*)edge_feat + e * 16;
#pragma unroll
                for (int kk = 0; kk < 16; kk++) {
                    float4 x = rp[kk];
                    acc += x.x * wvv[kk].x + x.y * wvv[kk].y + x.z * wvv[kk].z + x.w * wvv[kk].w;
                }
            }
            vmax = fmaxf(vmax, acc > 0.f ? acc : __expf(acc) - 1.f);
        }
        edge_max[(long)n * OUT_DIM + col] = __float2bfloat16(deg > 0 ? vmax : 0.f);
    }
}

// ---------- gated fusion (in-place over h_node) ----------
#define GATE_ROWS 8
__global__ __launch_bounds__(128) void k_gate(bf16* __restrict__ h_node,
                                              const bf16* __restrict__ edge_max,
                                              const float* __restrict__ w) {
    __shared__ float hn[GATE_ROWS][OUT_DIM];
    __shared__ float em[GATE_ROWS][OUT_DIM];
    int col = threadIdx.x;
    long row0 = (long)blockIdx.x * GATE_ROWS;
    for (int i = col; i < GATE_ROWS * OUT_DIM; i += 128) {
        hn[i >> 7][i & 127] = b2f(h_node[row0 * OUT_DIM + i]);
        em[i >> 7][i & 127] = b2f(edge_max[row0 * OUT_DIM + i]);
    }
    __syncthreads();
    float acc[GATE_ROWS];
    float bg = w[OFF_BGATE + col];
#pragma unroll
    for (int r = 0; r < GATE_ROWS; r++) acc[r] = bg;
    for (int k = 0; k < OUT_DIM; k++) {
        float wv = w[OFF_WGATE + k * OUT_DIM + col];
#pragma unroll
        for (int r = 0; r < GATE_ROWS; r++) acc[r] += hn[r][k] * wv;
    }
    for (int k = 0; k < OUT_DIM; k++) {
        float wv = w[OFF_WGATE + (OUT_DIM + k) * OUT_DIM + col];
#pragma unroll
        for (int r = 0; r < GATE_ROWS; r++) acc[r] += em[r][k] * wv;
    }
#pragma unroll
    for (int r = 0; r < GATE_ROWS; r++) {
        float g = 1.f / (1.f + expf(-acc[r]));
        h_node[(row0 + r) * OUT_DIM + col] = __float2bfloat16(g * hn[r][col] + (1.f - g) * em[r][col]);
    }
}

// ---------- output projection ----------
__global__ __launch_bounds__(128) void k_out(const bf16* __restrict__ h_fused,
                                             const float* __restrict__ w, const int* __restrict__ flag,
                                             bf16* __restrict__ out_b, float* __restrict__ out_f) {
    __shared__ float lds[PROJ_ROWS][OUT_DIM];
    int isbf = flag[0];
    int col = threadIdx.x;
    long row0 = (long)blockIdx.x * PROJ_ROWS;
    for (int i = col; i < PROJ_ROWS * OUT_DIM; i += 128)
        lds[i >> 7][i & 127] = b2f(h_fused[row0 * OUT_DIM + i]);
    __syncthreads();
    float acc[PROJ_ROWS];
    float bv = w[OFF_BOUT + col];
#pragma unroll
    for (int r = 0; r < PROJ_ROWS; r++) acc[r] = bv;
    for (int k = 0; k < OUT_DIM; k++) {
        float wv = w[OFF_WOUT + k * OUT_DIM + col];
#pragma unroll
        for (int r = 0; r < PROJ_ROWS; r++) acc[r] += lds[r][k] * wv;
    }
#pragma unroll
    for (int r = 0; r < PROJ_ROWS; r++) {
        long idx = (row0 + r) * OUT_DIM + col;
        if (isbf) out_b[idx] = __float2bfloat16(acc[r]);
        else      out_f[idx] = acc[r];
    }
}

extern "C" void kernel_launch(void* const* d_in, const int* in_sizes, int n_in,
                              void* d_out, int out_size, void* d_ws, size_t ws_size,
                              hipStream_t stream) {
    const void* node_feat = d_in[0];
    const void* edge_feat = d_in[1];
    const int* src = (const int*)d_in[2];
    const int* dst = (const int*)d_in[3];

    // workspace layout (bytes), total ~49.0 MB (proven-safe < 59.6 MB):
    //   0        .. 12.8M : f_src   bf16 [N][128]
    //   12.8M    .. 25.6M : f_dst   bf16 [N][128]  -> overlaid by edge_max bf16 after k_logits
    //   25.6M    .. 32.0M : logits  bf16 [E][4]
    //   32.0M    .. 44.8M : h_node  bf16 [N][128]  (h_fused in-place)
    //   44.8M    ..       : deg, rowptr, cursor, perm, wcanon, flag
    char* ws = (char*)d_ws;
    bf16* f_src = (bf16*)ws;
    bf16* f_dst = (bf16*)(ws + 12800000);
    bf16* edge_max = (bf16*)(ws + 12800000);  // overlays f_dst (dead after k_logits)
    bf16* logits = (bf16*)(ws + 25600000);
    bf16* h_node = (bf16*)(ws + 32000000);
    int* deg = (int*)(ws + 44800000);
    int* rowptr = (int*)(ws + 45000000);
    int* cursor = (int*)(ws + 45200008);
    int* perm = (int*)(ws + 45400016);
    float* wcanon = (float*)(ws + 48600032);
    int* flag = (int*)(ws + 48996320);

    bf16* out_b = (bf16*)d_out;
    float* out_f = (float*)d_out;
    bf16* out_a_b = out_b + (size_t)N_NODES * OUT_DIM;
    float* out_a_f = out_f + (size_t)N_NODES * OUT_DIM;

    k_detect<<<1, 256, 0, stream>>>(node_feat, flag);
    k_wconv<<<(W_TOTAL + 255) / 256, 256, 0, stream>>>(d_in[4], d_in[5], d_in[6], d_in[7], d_in[8],
                                                       d_in[9], d_in[10], d_in[11], d_in[12],
                                                       d_in[13], d_in[14], wcanon, flag);
    k_zero<<<(N_NODES + 255) / 256, 256, 0, stream>>>(deg);
    k_hist<<<(N_EDGES + 255) / 256, 256, 0, stream>>>(dst, deg);
    k_scan<<<1, 1024, 0, stream>>>(deg, rowptr, cursor);
    k_permute<<<(N_EDGES + 255) / 256, 256, 0, stream>>>(dst, cursor, perm);
    k_proj<<<N_NODES / PROJ_ROWS, 128, 0, stream>>>(node_feat, wcanon, flag, f_src, f_dst);
    k_logits<<<(N_EDGES * HEADS + 255) / 256, 256, 0, stream>>>(f_src, f_dst, src, dst, wcanon, logits);
    k_node_agg<<<N_NODES / 4, 256, 0, stream>>>(rowptr, perm, src, f_src, logits, edge_feat,
                                                wcanon, flag, h_node, edge_max, out_a_b, out_a_f);
    k_gate<<<N_NODES / GATE_ROWS, 128, 0, stream>>>(h_node, edge_max, wcanon);
    k_out<<<N_NODES / PROJ_ROWS, 128, 0, stream>>>(h_node, wcanon, flag, out_b, out_f);
}

// Round 2
// 966.922 us; speedup vs baseline: 1.6772x; 1.2425x over previous
//
#include <hip/hip_runtime.h>
#include <hip/hip_bf16.h>

// AdaptiveEdgeGAT: N=50000, E=800000, IN=OUT=128, EDGE=64, H=4, D=32
// CSR (sort-by-dst) + gather-based segmented reductions: zero data-path atomics.
// Dual-mode input read (bf16 or f32, device-detected), f32 accumulation.
// R1: k_node_agg wave-per-node (4 nodes/block, reg softmax, 4x-unrolled gather).
// R2: edge-encoder GEMM moved to MFMA 16x16x32 bf16 (A=W^T prepacked fragments,
//     B=edge_feat loaded direct from global; permutation-symmetric k-packing so
//     result is invariant to HW k-order). xs LDS staging deleted -> 7KB LDS,
//     zero barriers. k_logits vectorized (dwordx4 instead of 64 scalar loads).

#define N_NODES 50000
#define N_EDGES 800000
#define IN_DIM 128
#define OUT_DIM 128
#define EDGE_DIM 64
#define HEADS 4
#define HEAD_DIM 32
#define NEG_SLOPE 0.2f

typedef __hip_bfloat16 bf16;
typedef unsigned short u16;
typedef unsigned int u32;
typedef unsigned long long u64;
typedef __attribute__((ext_vector_type(8))) short bf16x8;
typedef __attribute__((ext_vector_type(4))) float f32x4;

// canonical f32 weight-block offsets (floats)
#define OFF_WSRC 0
#define OFF_BSRC 16384
#define OFF_WDST 16512
#define OFF_BDST 32896
#define OFF_ATTN 33024
#define OFF_WEDGE 33152
#define OFF_BEDGE 41344
#define OFF_WGATE 41472
#define OFF_BGATE 74240
#define OFF_WOUT 74368
#define OFF_BOUT 90752
#define OFF_WEDGE_T 90880   // transposed W_edge: [col][k] = [128][64] (f32, cold path)
#define OFF_WFRAG 99072     // bf16 A-operand fragments of W_edge^T: 4096 u32 words (16KB)
#define W_TOTAL 103168

__device__ __forceinline__ float b2f_raw(u16 v) {
    return __uint_as_float(((u32)v) << 16);
}
__device__ __forceinline__ float b2f(bf16 v) { return __bfloat162float(v); }
__device__ __forceinline__ float loadin(const void* p, long i, int isbf) {
    return isbf ? b2f_raw(((const u16*)p)[i]) : ((const float*)p)[i];
}
__device__ __forceinline__ float lo16(u32 v) { return __uint_as_float(v << 16); }
__device__ __forceinline__ float hi16(u32 v) { return __uint_as_float(v & 0xFFFF0000u); }
__device__ __forceinline__ u16 f2b_bits(float x) {
    bf16 t = __float2bfloat16(x);
    return *reinterpret_cast<u16*>(&t);
}

// ---------- dtype detector ----------
__global__ __launch_bounds__(256) void k_detect(const void* node, int* flag) {
    __shared__ int cnt[256];
    int c = 0;
    for (int i = threadIdx.x; i < 8192; i += 256) {
        float v = b2f_raw(((const u16*)node)[i]);
        float a = fabsf(v);
        if ((a >= 1e-4f && a <= 50.f) || v == 0.f) c++;
    }
    cnt[threadIdx.x] = c;
    __syncthreads();
    for (int s = 128; s > 0; s >>= 1) {
        if (threadIdx.x < s) cnt[threadIdx.x] += cnt[threadIdx.x + s];
        __syncthreads();
    }
    if (threadIdx.x == 0) flag[0] = (cnt[0] >= (8192 * 85) / 100) ? 1 : 0;
}

// ---------- canonicalize weights to f32 (+ W_edge^T + bf16 MFMA fragments) ----------
__global__ __launch_bounds__(256) void k_wconv(const void* Wsrc, const void* bsrc,
                                               const void* Wdst, const void* bdst,
                                               const void* attn, const void* Wedge, const void* bedge,
                                               const void* Wgate, const void* bgate,
                                               const void* Wout, const void* bout,
                                               float* w, const int* flag) {
    int i = blockIdx.x * 256 + threadIdx.x;
    if (i >= W_TOTAL) return;
    int f = flag[0];
    const void* p; long off;
    if (i < OFF_BSRC)         { p = Wsrc;  off = i - OFF_WSRC; }
    else if (i < OFF_WDST)    { p = bsrc;  off = i - OFF_BSRC; }
    else if (i < OFF_BDST)    { p = Wdst;  off = i - OFF_WDST; }
    else if (i < OFF_ATTN)    { p = bdst;  off = i - OFF_BDST; }
    else if (i < OFF_WEDGE)   { p = attn;  off = i - OFF_ATTN; }
    else if (i < OFF_BEDGE)   { p = Wedge; off = i - OFF_WEDGE; }
    else if (i < OFF_WGATE)   { p = bedge; off = i - OFF_BEDGE; }
    else if (i < OFF_BGATE)   { p = Wgate; off = i - OFF_WGATE; }
    else if (i < OFF_WOUT)    { p = bgate; off = i - OFF_BGATE; }
    else if (i < OFF_BOUT)    { p = Wout;  off = i - OFF_WOUT; }
    else if (i < OFF_WEDGE_T) { p = bout;  off = i - OFF_BOUT; }
    else if (i < OFF_WFRAG) { // transposed W_edge: wt[col*64+k] = W_edge[k*128+col]
        int idx = i - OFF_WEDGE_T;
        int col = idx >> 6, k = idx & 63;
        w[i] = loadin(Wedge, (long)k * OUT_DIM + col, f);
        return;
    } else {
        // bf16 A-operand fragment prepack (u32 word = 2 bf16 slots).
        // word layout: wdx = mt*512 + tt*256 + l*4 + s/2
        //   lane l slot s  <->  A[col = mt*16 + (l&15)][k = tt*32 + 8*(l>>4) + s]
        int wdx = i - OFF_WFRAG;
        int sp = (wdx & 3) * 2;
        int l = (wdx >> 2) & 63;
        int tt = (wdx >> 8) & 1;
        int mt = wdx >> 9;
        int k0 = tt * 32 + ((l >> 4) << 3);
        int col = mt * 16 + (l & 15);
        float v0 = loadin(Wedge, (long)(k0 + sp) * OUT_DIM + col, f);
        float v1 = loadin(Wedge, (long)(k0 + sp + 1) * OUT_DIM + col, f);
        *(u32*)&w[i] = (u32)f2b_bits(v0) | ((u32)f2b_bits(v1) << 16);
        return;
    }
    w[i] = loadin(p, off, f);
}

// ---------- zero degree counters ----------
__global__ __launch_bounds__(256) void k_zero(int* __restrict__ deg) {
    int i = blockIdx.x * 256 + threadIdx.x;
    if (i < N_NODES) deg[i] = 0;
}

// ---------- degree histogram ----------
__global__ __launch_bounds__(256) void k_hist(const int* __restrict__ dst, int* __restrict__ deg) {
    int e = blockIdx.x * 256 + threadIdx.x;
    if (e < N_EDGES) atomicAdd(&deg[dst[e]], 1);
}

// ---------- exclusive prefix sum (single block) -> rowptr, cursor ----------
__global__ __launch_bounds__(1024) void k_scan(const int* __restrict__ deg,
                                               int* __restrict__ rowptr,
                                               int* __restrict__ cursor) {
    __shared__ int buf[1024];
    __shared__ int carry;
    int tid = threadIdx.x;
    if (tid == 0) carry = 0;
    __syncthreads();
    for (int base = 0; base <= N_NODES; base += 1024) {
        int i = base + tid;
        int v = (i < N_NODES) ? deg[i] : 0;
        buf[tid] = v;
        __syncthreads();
        for (int s = 1; s < 1024; s <<= 1) {
            int add = (tid >= s) ? buf[tid - s] : 0;
            __syncthreads();
            buf[tid] += add;
            __syncthreads();
        }
        int excl = carry + buf[tid] - v;
        if (i <= N_NODES) {
            rowptr[i] = excl;
            if (i < N_NODES) cursor[i] = excl;
        }
        __syncthreads();
        if (tid == 1023) carry += buf[1023];
        __syncthreads();
    }
}

// ---------- scatter edge ids into dst-sorted order ----------
__global__ __launch_bounds__(256) void k_permute(const int* __restrict__ dst,
                                                 int* __restrict__ cursor, int* __restrict__ perm) {
    int e = blockIdx.x * 256 + threadIdx.x;
    if (e >= N_EDGES) return;
    int p = atomicAdd(&cursor[dst[e]], 1);
    perm[p] = e;
}

// ---------- node projections ----------
#define PROJ_ROWS 16
__global__ __launch_bounds__(128) void k_proj(const void* __restrict__ node,
                                              const float* __restrict__ w, const int* __restrict__ flag,
                                              bf16* __restrict__ f_src, bf16* __restrict__ f_dst) {
    __shared__ float lds[PROJ_ROWS][IN_DIM];
    int isbf = flag[0];
    int col = threadIdx.x;
    long row0 = (long)blockIdx.x * PROJ_ROWS;
    for (int i = col; i < PROJ_ROWS * IN_DIM; i += 128)
        lds[i >> 7][i & 127] = loadin(node, row0 * IN_DIM + i, isbf);
    __syncthreads();
    float accs[PROJ_ROWS], accd[PROJ_ROWS];
    float bsv = w[OFF_BSRC + col], bdv = w[OFF_BDST + col];
#pragma unroll
    for (int r = 0; r < PROJ_ROWS; r++) { accs[r] = bsv; accd[r] = bdv; }
    for (int k = 0; k < IN_DIM; k++) {
        float ws = w[OFF_WSRC + k * OUT_DIM + col];
        float wd = w[OFF_WDST + k * OUT_DIM + col];
#pragma unroll
        for (int r = 0; r < PROJ_ROWS; r++) {
            float x = lds[r][k];
            accs[r] += x * ws;
            accd[r] += x * wd;
        }
    }
#pragma unroll
    for (int r = 0; r < PROJ_ROWS; r++) {
        f_src[(row0 + r) * OUT_DIM + col] = __float2bfloat16(accs[r]);
        f_dst[(row0 + r) * OUT_DIM + col] = __float2bfloat16(accd[r]);
    }
}

// ---------- per-edge GATv2 logits (vectorized loads) ----------
__global__ __launch_bounds__(256) void k_logits(const bf16* __restrict__ f_src,
                                                const bf16* __restrict__ f_dst,
                                                const int* __restrict__ src, const int* __restrict__ dst,
                                                const float* __restrict__ w,
                                                bf16* __restrict__ logits) {
    __shared__ float aw[HEADS * HEAD_DIM];
    if (threadIdx.x < HEADS * HEAD_DIM) aw[threadIdx.x] = w[OFF_ATTN + threadIdx.x];
    __syncthreads();
    int t = blockIdx.x * 256 + threadIdx.x;
    int e = t >> 2, h = t & 3;
    if (e >= N_EDGES) return;
    int s = src[e], d = dst[e];
    const uint4* ps = (const uint4*)(f_src + (long)s * OUT_DIM + h * HEAD_DIM);
    const uint4* pd = (const uint4*)(f_dst + (long)d * OUT_DIM + h * HEAD_DIM);
    const float* awh = &aw[h * HEAD_DIM];
    float acc = 0.f;
#pragma unroll
    for (int q = 0; q < 4; q++) {
        uint4 a = ps[q], b = pd[q];
        u32 aa[4] = {a.x, a.y, a.z, a.w};
        u32 bb[4] = {b.x, b.y, b.z, b.w};
#pragma unroll
        for (int c2 = 0; c2 < 4; c2++) {
            float v0 = lo16(aa[c2]) + lo16(bb[c2]);
            float v1 = hi16(aa[c2]) + hi16(bb[c2]);
            v0 = v0 > 0.f ? v0 : NEG_SLOPE * v0;
            v1 = v1 > 0.f ? v1 : NEG_SLOPE * v1;
            acc += v0 * awh[q * 8 + c2 * 2] + v1 * awh[q * 8 + c2 * 2 + 1];
        }
    }
    logits[(long)e * HEADS + h] = __float2bfloat16(acc);
}

// ---------- per-node aggregation: wave-per-node, 4 nodes per 256-thr block ----------
// All LDS is wave-private -> no barriers. Edge-encoder GEMM runs on MFMA:
//   D[col][edge] = sum_k W_edge[k][col] * edge_feat[edge][k]
// A-fragments (W^T) prepacked bf16 in wcanon; B-fragments loaded from global
// edge_feat with the SAME slot->k mapping (k-order-invariant by symmetry).
__global__ __launch_bounds__(256, 4) void k_node_agg(const int* __restrict__ rowptr,
                                                  const int* __restrict__ perm,
                                                  const int* __restrict__ src,
                                                  const bf16* __restrict__ f_src,
                                                  const bf16* __restrict__ logits,
                                                  const void* __restrict__ edge_feat,
                                                  const float* __restrict__ w, const int* __restrict__ flag,
                                                  bf16* __restrict__ h_node, bf16* __restrict__ edge_max,
                                                  bf16* __restrict__ out_a_b, float* __restrict__ out_a_f) {
    __shared__ int s_esrc[4][64];
    __shared__ __align__(16) float s_a[4][64][4];
    __shared__ __align__(16) float s_vmax[4][128];

    const int wv = threadIdx.x >> 6;
    const int lane = threadIdx.x & 63;
    const int n = blockIdx.x * 4 + wv;
    const int isbf = flag[0];
    const int r0 = rowptr[n], r1 = rowptr[n + 1];
    const int deg = r1 - r0;

    int* esrc = s_esrc[wv];
    float (*aA)[4] = s_a[wv];
    float* vm = s_vmax[wv];

    // ---- Phase 1: per-lane edge metadata ----
    int e0 = 0;
    float l0 = -3.0e38f, l1 = -3.0e38f, l2 = -3.0e38f, l3 = -3.0e38f;
    if (lane < deg) {
        e0 = perm[r0 + lane];
        esrc[lane] = src[e0];
        u64 lw = ((const u64*)logits)[e0];
        l0 = b2f_raw((u16)lw);
        l1 = b2f_raw((u16)(lw >> 16));
        l2 = b2f_raw((u16)(lw >> 32));
        l3 = b2f_raw((u16)(lw >> 48));
    }

    // ---- Phase 2: softmax stats in registers ----
    float m0 = l0, m1 = l1, m2 = l2, m3 = l3;
    for (int j = lane + 64; j < deg; j += 64) {   // cold: deg > 64
        u64 lw = ((const u64*)logits)[perm[r0 + j]];
        m0 = fmaxf(m0, b2f_raw((u16)lw));
        m1 = fmaxf(m1, b2f_raw((u16)(lw >> 16)));
        m2 = fmaxf(m2, b2f_raw((u16)(lw >> 32)));
        m3 = fmaxf(m3, b2f_raw((u16)(lw >> 48)));
    }
#pragma unroll
    for (int s = 1; s < 64; s <<= 1) {
        m0 = fmaxf(m0, __shfl_xor(m0, s));
        m1 = fmaxf(m1, __shfl_xor(m1, s));
        m2 = fmaxf(m2, __shfl_xor(m2, s));
        m3 = fmaxf(m3, __shfl_xor(m3, s));
    }
    float p0 = 0.f, p1 = 0.f, p2 = 0.f, p3 = 0.f;
    if (lane < deg) {
        p0 = __expf(l0 - m0); p1 = __expf(l1 - m1);
        p2 = __expf(l2 - m2); p3 = __expf(l3 - m3);
    }
    float t0 = p0, t1 = p1, t2 = p2, t3 = p3;
    for (int j = lane + 64; j < deg; j += 64) {   // cold
        u64 lw = ((const u64*)logits)[perm[r0 + j]];
        t0 += __expf(b2f_raw((u16)lw) - m0);
        t1 += __expf(b2f_raw((u16)(lw >> 16)) - m1);
        t2 += __expf(b2f_raw((u16)(lw >> 32)) - m2);
        t3 += __expf(b2f_raw((u16)(lw >> 48)) - m3);
    }
#pragma unroll
    for (int s = 1; s < 64; s <<= 1) {
        t0 += __shfl_xor(t0, s);
        t1 += __shfl_xor(t1, s);
        t2 += __shfl_xor(t2, s);
        t3 += __shfl_xor(t3, s);
    }
    const float i0 = 1.f / fmaxf(t0, 1e-9f);
    const float i1 = 1.f / fmaxf(t1, 1e-9f);
    const float i2 = 1.f / fmaxf(t2, 1e-9f);
    const float i3 = 1.f / fmaxf(t3, 1e-9f);
    if (lane < deg) {
        float a0 = p0 * i0, a1 = p1 * i1, a2 = p2 * i2, a3 = p3 * i3;
        *(float4*)aA[lane] = make_float4(a0, a1, a2, a3);
        if (isbf) {
            u64 pk = (u64)f2b_bits(a0) | ((u64)f2b_bits(a1) << 16)
                   | ((u64)f2b_bits(a2) << 32) | ((u64)f2b_bits(a3) << 48);
            ((u64*)out_a_b)[e0] = pk;
        } else {
            ((float4*)out_a_f)[e0] = make_float4(a0, a1, a2, a3);
        }
    }
    for (int j = lane + 64; j < deg; j += 64) {   // cold: out_a for overflow edges
        int e = perm[r0 + j];
        u64 lw = ((const u64*)logits)[e];
        float a0 = __expf(b2f_raw((u16)lw) - m0) * i0;
        float a1 = __expf(b2f_raw((u16)(lw >> 16)) - m1) * i1;
        float a2 = __expf(b2f_raw((u16)(lw >> 32)) - m2) * i2;
        float a3 = __expf(b2f_raw((u16)(lw >> 48)) - m3) * i3;
        if (isbf) {
            u64 pk = (u64)f2b_bits(a0) | ((u64)f2b_bits(a1) << 16)
                   | ((u64)f2b_bits(a2) << 32) | ((u64)f2b_bits(a3) << 48);
            ((u64*)out_a_b)[e] = pk;
        } else {
            ((float4*)out_a_f)[e] = make_float4(a0, a1, a2, a3);
        }
    }

    // (no barrier: all LDS is wave-private and waves are lockstep)

    // ---- Phase 3a: message gather. lane owns bf16 column pair (2*lane, 2*lane+1) ----
    const int hsel = lane >> 4;               // head of this column pair
    const u32* fs32 = (const u32*)f_src;
    float acc0 = 0.f, acc1 = 0.f;
    const int dm = deg < 64 ? deg : 64;
    int j = 0;
    for (; j + 4 <= dm; j += 4) {
        int s0 = esrc[j], s1 = esrc[j + 1], s2 = esrc[j + 2], s3 = esrc[j + 3];
        float a0 = aA[j][hsel], a1 = aA[j + 1][hsel];
        float a2 = aA[j + 2][hsel], a3 = aA[j + 3][hsel];
        u32 v0 = fs32[s0 * 64 + lane];
        u32 v1 = fs32[s1 * 64 + lane];
        u32 v2 = fs32[s2 * 64 + lane];
        u32 v3 = fs32[s3 * 64 + lane];
        acc0 += lo16(v0) * a0 + lo16(v1) * a1 + lo16(v2) * a2 + lo16(v3) * a3;
        acc1 += hi16(v0) * a0 + hi16(v1) * a1 + hi16(v2) * a2 + hi16(v3) * a3;
    }
    for (; j < dm; j++) {
        int s0 = esrc[j];
        float a0 = aA[j][hsel];
        u32 v0 = fs32[s0 * 64 + lane];
        acc0 += lo16(v0) * a0;
        acc1 += hi16(v0) * a0;
    }
    if (deg > 64) {   // cold
        float mh = (hsel & 2) ? ((hsel & 1) ? m3 : m2) : ((hsel & 1) ? m1 : m0);
        float ih = (hsel & 2) ? ((hsel & 1) ? i3 : i2) : ((hsel & 1) ? i1 : i0);
        for (int jj = 64; jj < deg; jj++) {
            int e = perm[r0 + jj];
            int s0 = src[e];
            float lg = b2f_raw(((const u16*)logits)[(long)e * 4 + hsel]);
            float aj = __expf(lg - mh) * ih;
            u32 v0 = fs32[s0 * 64 + lane];
            acc0 += lo16(v0) * aj;
            acc1 += hi16(v0) * aj;
        }
    }
    ((u32*)h_node)[n * 64 + lane] =
        (u32)f2b_bits(acc0) | ((u32)f2b_bits(acc1) << 16);

    // ---- Phase 3b: edge encoder GEMM on MFMA + column max ----
    if (deg == 0) {
        ((u32*)edge_max)[(long)n * 64 + lane] = 0u;
        return;
    }
    {
        const bf16x8* wfb = (const bf16x8*)(w + OFF_WFRAG);
        const int g = lane >> 4;
        const int ntiles = deg >= 64 ? 4 : ((deg + 15) >> 4);
        for (int nt = 0; nt < ntiles; nt++) {
            const int je = nt * 16 + (lane & 15);
            const int ej = __shfl(e0, je);      // e0 defaults 0 for pad lanes (masked below)
            bf16x8 bf0, bf1;
            if (isbf) {
                const uint4* ef = (const uint4*)edge_feat;
                uint4 q0 = ef[(long)ej * 8 + g];
                uint4 q1 = ef[(long)ej * 8 + 4 + g];
                bf0 = *reinterpret_cast<bf16x8*>(&q0);
                bf1 = *reinterpret_cast<bf16x8*>(&q1);
            } else {
                const float4* ef = (const float4*)edge_feat;
                long base = (long)ej * 16 + g * 2;
                float4 x0 = ef[base], x1 = ef[base + 1];
                float4 y0 = ef[base + 8], y1 = ef[base + 9];
                bf0[0] = (short)f2b_bits(x0.x); bf0[1] = (short)f2b_bits(x0.y);
                bf0[2] = (short)f2b_bits(x0.z); bf0[3] = (short)f2b_bits(x0.w);
                bf0[4] = (short)f2b_bits(x1.x); bf0[5] = (short)f2b_bits(x1.y);
                bf0[6] = (short)f2b_bits(x1.z); bf0[7] = (short)f2b_bits(x1.w);
                bf1[0] = (short)f2b_bits(y0.x); bf1[1] = (short)f2b_bits(y0.y);
                bf1[2] = (short)f2b_bits(y0.z); bf1[3] = (short)f2b_bits(y0.w);
                bf1[4] = (short)f2b_bits(y1.x); bf1[5] = (short)f2b_bits(y1.y);
                bf1[6] = (short)f2b_bits(y1.z); bf1[7] = (short)f2b_bits(y1.w);
            }
            const bool valid = je < deg;
#pragma unroll
            for (int mt = 0; mt < 8; mt++) {
                float4 b4 = *(const float4*)(w + OFF_BEDGE + mt * 16 + g * 4);
                f32x4 c = {b4.x, b4.y, b4.z, b4.w};   // bias rides in C-init
                c = __builtin_amdgcn_mfma_f32_16x16x32_bf16(wfb[(mt * 2 + 0) * 64 + lane], bf0, c, 0, 0, 0);
                c = __builtin_amdgcn_mfma_f32_16x16x32_bf16(wfb[(mt * 2 + 1) * 64 + lane], bf1, c, 0, 0, 0);
                float v0 = c[0], v1 = c[1], v2 = c[2], v3 = c[3];
                v0 = v0 > 0.f ? v0 : __expf(v0) - 1.f;
                v1 = v1 > 0.f ? v1 : __expf(v1) - 1.f;
                v2 = v2 > 0.f ? v2 : __expf(v2) - 1.f;
                v3 = v3 > 0.f ? v3 : __expf(v3) - 1.f;
                if (!valid) { v0 = v1 = v2 = v3 = -3.0e38f; }
#pragma unroll
                for (int mm = 1; mm < 16; mm <<= 1) {
                    v0 = fmaxf(v0, __shfl_xor(v0, mm));
                    v1 = fmaxf(v1, __shfl_xor(v1, mm));
                    v2 = fmaxf(v2, __shfl_xor(v2, mm));
                    v3 = fmaxf(v3, __shfl_xor(v3, mm));
                }
                if ((lane & 15) == 0) {
                    float4* vp = (float4*)&vm[mt * 16 + g * 4];
                    if (nt == 0) {
                        *vp = make_float4(v0, v1, v2, v3);
                    } else {
                        float4 o = *vp;
                        *vp = make_float4(fmaxf(o.x, v0), fmaxf(o.y, v1),
                                          fmaxf(o.z, v2), fmaxf(o.w, v3));
                    }
                }
            }
        }
        if (deg > 64) {   // ultra-cold overflow: scalar per-column path
            for (int jj = 64; jj < deg; jj++) {
                long e = perm[r0 + jj];
#pragma unroll 1
                for (int p = 0; p < 2; p++) {
                    int col = lane + p * 64;
                    const float4* wt4 = (const float4*)(w + OFF_WEDGE_T + col * EDGE_DIM);
                    float acc = w[OFF_BEDGE + col];
                    for (int kk = 0; kk < 16; kk++) {
                        float4 wv4 = wt4[kk];
                        float xx, xy, xz, xw;
                        if (isbf) {
                            u64 q = ((const u64*)edge_feat)[e * 16 + kk];
                            xx = b2f_raw((u16)q); xy = b2f_raw((u16)(q >> 16));
                            xz = b2f_raw((u16)(q >> 32)); xw = b2f_raw((u16)(q >> 48));
                        } else {
                            float4 xf = ((const float4*)edge_feat)[e * 16 + kk];
                            xx = xf.x; xy = xf.y; xz = xf.z; xw = xf.w;
                        }
                        acc += xx * wv4.x + xy * wv4.y + xz * wv4.z + xw * wv4.w;
                    }
                    float el = acc > 0.f ? acc : __expf(acc) - 1.f;
                    vm[col] = fmaxf(vm[col], el);
                }
            }
        }
        float2 vv = *(float2*)&vm[lane * 2];
        ((u32*)edge_max)[(long)n * 64 + lane] =
            (u32)f2b_bits(vv.x) | ((u32)f2b_bits(vv.y) << 16);
    }
}

// ---------- gated fusion (in-place over h_node) ----------
#define GATE_ROWS 8
__global__ __launch_bounds__(128) void k_gate(bf16* __restrict__ h_node,
                                              const bf16* __restrict__ edge_max,
                                              const float* __restrict__ w) {
    __shared__ float hn[GATE_ROWS][OUT_DIM];
    __shared__ float em[GATE_ROWS][OUT_DIM];
    int col = threadIdx.x;
    long row0 = (long)blockIdx.x * GATE_ROWS;
    for (int i = col; i < GATE_ROWS * OUT_DIM; i += 128) {
        hn[i >> 7][i & 127] = b2f(h_node[row0 * OUT_DIM + i]);
        em[i >> 7][i & 127] = b2f(edge_max[row0 * OUT_DIM + i]);
    }
    __syncthreads();
    float acc[GATE_ROWS];
    float bg = w[OFF_BGATE + col];
#pragma unroll
    for (int r = 0; r < GATE_ROWS; r++) acc[r] = bg;
    for (int k = 0; k < OUT_DIM; k++) {
        float wv = w[OFF_WGATE + k * OUT_DIM + col];
#pragma unroll
        for (int r = 0; r < GATE_ROWS; r++) acc[r] += hn[r][k] * wv;
    }
    for (int k = 0; k < OUT_DIM; k++) {
        float wv = w[OFF_WGATE + (OUT_DIM + k) * OUT_DIM + col];
#pragma unroll
        for (int r = 0; r < GATE_ROWS; r++) acc[r] += em[r][k] * wv;
    }
#pragma unroll
    for (int r = 0; r < GATE_ROWS; r++) {
        float g = 1.f / (1.f + expf(-acc[r]));
        h_node[(row0 + r) * OUT_DIM + col] = __float2bfloat16(g * hn[r][col] + (1.f - g) * em[r][col]);
    }
}

// ---------- output projection ----------
__global__ __launch_bounds__(128) void k_out(const bf16* __restrict__ h_fused,
                                             const float* __restrict__ w, const int* __restrict__ flag,
                                             bf16* __restrict__ out_b, float* __restrict__ out_f) {
    __shared__ float lds[PROJ_ROWS][OUT_DIM];
    int isbf = flag[0];
    int col = threadIdx.x;
    long row0 = (long)blockIdx.x * PROJ_ROWS;
    for (int i = col; i < PROJ_ROWS * OUT_DIM; i += 128)
        lds[i >> 7][i & 127] = b2f(h_fused[row0 * OUT_DIM + i]);
    __syncthreads();
    float acc[PROJ_ROWS];
    float bv = w[OFF_BOUT + col];
#pragma unroll
    for (int r = 0; r < PROJ_ROWS; r++) acc[r] = bv;
    for (int k = 0; k < OUT_DIM; k++) {
        float wv = w[OFF_WOUT + k * OUT_DIM + col];
#pragma unroll
        for (int r = 0; r < PROJ_ROWS; r++) acc[r] += lds[r][k] * wv;
    }
#pragma unroll
    for (int r = 0; r < PROJ_ROWS; r++) {
        long idx = (row0 + r) * OUT_DIM + col;
        if (isbf) out_b[idx] = __float2bfloat16(acc[r]);
        else      out_f[idx] = acc[r];
    }
}

extern "C" void kernel_launch(void* const* d_in, const int* in_sizes, int n_in,
                              void* d_out, int out_size, void* d_ws, size_t ws_size,
                              hipStream_t stream) {
    const void* node_feat = d_in[0];
    const void* edge_feat = d_in[1];
    const int* src = (const int*)d_in[2];
    const int* dst = (const int*)d_in[3];

    // workspace layout (bytes), total ~49.0 MB (proven-safe < 59.6 MB):
    //   0        .. 12.8M : f_src   bf16 [N][128]
    //   12.8M    .. 25.6M : f_dst   bf16 [N][128]  -> overlaid by edge_max bf16 after k_logits
    //   25.6M    .. 32.0M : logits  bf16 [E][4]
    //   32.0M    .. 44.8M : h_node  bf16 [N][128]  (h_fused in-place)
    //   44.8M    ..       : deg, rowptr, cursor, perm, wcanon(+frag), flag
    char* ws = (char*)d_ws;
    bf16* f_src = (bf16*)ws;
    bf16* f_dst = (bf16*)(ws + 12800000);
    bf16* edge_max = (bf16*)(ws + 12800000);  // overlays f_dst (dead after k_logits)
    bf16* logits = (bf16*)(ws + 25600000);
    bf16* h_node = (bf16*)(ws + 32000000);
    int* deg = (int*)(ws + 44800000);
    int* rowptr = (int*)(ws + 45000000);
    int* cursor = (int*)(ws + 45200008);
    int* perm = (int*)(ws + 45400016);
    float* wcanon = (float*)(ws + 48600032);
    int* flag = (int*)(ws + 49012704);

    bf16* out_b = (bf16*)d_out;
    float* out_f = (float*)d_out;
    bf16* out_a_b = out_b + (size_t)N_NODES * OUT_DIM;
    float* out_a_f = out_f + (size_t)N_NODES * OUT_DIM;

    k_detect<<<1, 256, 0, stream>>>(node_feat, flag);
    k_wconv<<<(W_TOTAL + 255) / 256, 256, 0, stream>>>(d_in[4], d_in[5], d_in[6], d_in[7], d_in[8],
                                                       d_in[9], d_in[10], d_in[11], d_in[12],
                                                       d_in[13], d_in[14], wcanon, flag);
    k_zero<<<(N_NODES + 255) / 256, 256, 0, stream>>>(deg);
    k_hist<<<(N_EDGES + 255) / 256, 256, 0, stream>>>(dst, deg);
    k_scan<<<1, 1024, 0, stream>>>(deg, rowptr, cursor);
    k_permute<<<(N_EDGES + 255) / 256, 256, 0, stream>>>(dst, cursor, perm);
    k_proj<<<N_NODES / PROJ_ROWS, 128, 0, stream>>>(node_feat, wcanon, flag, f_src, f_dst);
    k_logits<<<(N_EDGES * HEADS + 255) / 256, 256, 0, stream>>>(f_src, f_dst, src, dst, wcanon, logits);
    k_node_agg<<<N_NODES / 4, 256, 0, stream>>>(rowptr, perm, src, f_src, logits, edge_feat,
                                                wcanon, flag, h_node, edge_max, out_a_b, out_a_f);
    k_gate<<<N_NODES / GATE_ROWS, 128, 0, stream>>>(h_node, edge_max, wcanon);
    k_out<<<N_NODES / PROJ_ROWS, 128, 0, stream>>>(h_node, wcanon, flag, out_b, out_f);
}